// Round 16
// baseline (33.518 us; speedup 1.0000x reference)
//
#include <hip/hip_runtime.h>

#define N_NODES 30000
#define C 128
#define BM 64
#define NBLK 469   // ceil(30000/64)

typedef __attribute__((ext_vector_type(8))) short bf16x8;
typedef __attribute__((ext_vector_type(4))) float f32x4;

// ws layout:
//   shorts [0, 32768)        : B~t FRAGMENT-MAJOR bf16 [set][frag(32)][lane(64)][8]
//                              frag = (wj*4+ks)*2+nt ; lane = lk*16+l15
//                              B~ = wv^T (wp[:,:C] + wp[:,C:])^T  (masks==1 collapse, r12)
//   float 16384 + set*128    : cvS f32 [set][128] = cv_A + cv_B + bp
#define CVS_OFF_F(set) (16384 + (set) * 128)

__device__ __forceinline__ unsigned short f2bf(float f) {
  union { float f; unsigned int u; } v; v.f = f;
  unsigned int r = v.u + 0x7FFF + ((v.u >> 16) & 1);  // RNE
  return (unsigned short)(r >> 16);
}

// ---------------------------------------------------------------------------
// K1: prep. B~t fragment-major + cvS. grid (128, 2), block 128. (r14, verified)
// ---------------------------------------------------------------------------
__global__ void prep_kernel(const float* __restrict__ wv1, const float* __restrict__ bv1,
                            const float* __restrict__ wp1, const float* __restrict__ bp1,
                            const float* __restrict__ wv2, const float* __restrict__ bv2,
                            const float* __restrict__ wp2, const float* __restrict__ bp2,
                            float* __restrict__ ws) {
  const int k = blockIdx.x;   // GEMM k index 0..127
  const int set = blockIdx.y;
  const float* wv = set ? wv2 : wv1;
  const float* bv = set ? bv2 : bv1;
  const float* wp = set ? wp2 : wp1;
  const float* bp = set ? bp2 : bp1;

  __shared__ float wvcol[C];
  const int t = threadIdx.x;   // 0..127
  wvcol[t] = wv[t * C + k];
  __syncthreads();

  const int j = t;  // output col 0..127
  const float* wprow = wp + j * (2 * C);
  float s = 0.f;
#pragma unroll 4
  for (int c = 0; c < C; ++c) s += wvcol[c] * (wprow[c] + wprow[C + c]);

  const int wj  = j >> 5;
  const int nt  = (j >> 4) & 1;
  const int l15 = j & 15;
  const int ks  = k >> 5;
  const int lk  = (k >> 3) & 3;
  const int jj  = k & 7;
  const int frag = (wj * 4 + ks) * 2 + nt;
  const int lane = lk * 16 + l15;
  ((unsigned short*)ws)[set * 16384 + frag * 512 + lane * 8 + jj] = f2bf(s);

  if (k == 0) {
    float s2 = 0.f;
#pragma unroll 4
    for (int c = 0; c < C; ++c) s2 += bv[c] * (wprow[c] + wprow[C + c]);
    ws[CVS_OFF_F(set) + j] = s2 + bp[j];
  }
}

// ---------------------------------------------------------------------------
// K2: BARRIER-FREE wave-autonomous main. 256 thr = 4 waves; wave w owns rows
// i0 + w*16 + l15 and ALL 128 output cols. Private 4 KB LDS slice per wave
// (intra-wave ds ordering only -> NO __syncthreads anywhere).
//   stage own 16 rows (coalesced 512B runs) -> cvt -> swizzled ds_write;
//   B~ half-tiles (16 frags, 64 VGPR) from L2; 8 MFMA/ks x 4 ks; cvS at epilogue.
// grid (469, 2).
// ---------------------------------------------------------------------------
__global__ __launch_bounds__(256, 3) void main_kernel(
    const float* __restrict__ feat1, const float* __restrict__ feat2,
    const float* __restrict__ ws, float* __restrict__ out) {
  const int set = blockIdx.y;
  const float* feat = set ? feat2 : feat1;
  const unsigned short* Btf = (const unsigned short*)ws + (size_t)set * 16384;
  const float* cvS = ws + CVS_OFF_F(set);
  float* outp = out + (size_t)set * N_NODES * C;

  __shared__ unsigned short feat_s[4][16 * 128];  // 4 waves x 4 KB = 16 KB

  const int i0 = blockIdx.x * BM;
  const int tid = threadIdx.x;
  const int w = tid >> 6;      // wave 0..3
  const int lane = tid & 63;
  const int l15 = lane & 15;
  const int lk  = lane >> 4;
  const int rowbase = i0 + w * 16;

  // ---- (1) stage own 16 rows: 8 float4 loads (512B-contiguous runs/wave) ----
  float4 st[8];
#pragma unroll
  for (int ll = 0; ll < 4; ++ll) {
    const int c = lane + 64 * ll;   // 0..255 (32B f32 chunks)
    const int r = c >> 4;           // row 0..15
    const int q = c & 15;           // chunk in row
    int gi = rowbase + r;
    if (gi >= N_NODES) gi = N_NODES - 1;
    const float* src = feat + (size_t)gi * C + q * 8;
    st[2 * ll]     = *reinterpret_cast<const float4*>(src);
    st[2 * ll + 1] = *reinterpret_cast<const float4*>(src + 4);
  }

  // ---- (2) B~ half 1 (ks=0,1): 16 frags = 64 VGPR, 1KB coalesced L2 loads ----
  const unsigned short* bfrag = Btf + (size_t)lane * 8;
  bf16x8 breg[2][8];  // [ks&1][ct]  ct: col-tile 0..7 -> frag ((ct>>1)*4+ks)*2+(ct&1)
#pragma unroll
  for (int ksh = 0; ksh < 2; ++ksh)
#pragma unroll
    for (int ct = 0; ct < 8; ++ct)
      breg[ksh][ct] = *reinterpret_cast<const bf16x8*>(
          bfrag + (size_t)(((ct >> 1) * 4 + ksh) * 2 + (ct & 1)) * 512);

  // ---- (3) cvt + swizzled ds_write into private slice (no barrier) ----
  unsigned short* myl = feat_s[w];
#pragma unroll
  for (int ll = 0; ll < 4; ++ll) {
    const int c = lane + 64 * ll;
    const int r = c >> 4;
    const int q = c & 15;
    const float4 v0 = st[2 * ll];
    const float4 v1 = st[2 * ll + 1];
    bf16x8 h;
    h[0] = (short)f2bf(v0.x); h[1] = (short)f2bf(v0.y);
    h[2] = (short)f2bf(v0.z); h[3] = (short)f2bf(v0.w);
    h[4] = (short)f2bf(v1.x); h[5] = (short)f2bf(v1.y);
    h[6] = (short)f2bf(v1.z); h[7] = (short)f2bf(v1.w);
    int byte = r * 256 + q * 16;
    byte ^= ((r & 7) << 4);
    *reinterpret_cast<bf16x8*>(reinterpret_cast<char*>(myl) + byte) = h;
  }

  // ---- (4) compute: wave-private; compiler inserts lgkmcnt for ds dep ----
  f32x4 acc[8] = {};  // [ct]

#pragma unroll
  for (int ks = 0; ks < 4; ++ks) {
    if (ks == 2) {
      // B~ half 2 (ks=2,3)
#pragma unroll
      for (int ksh = 0; ksh < 2; ++ksh)
#pragma unroll
        for (int ct = 0; ct < 8; ++ct)
          breg[ksh][ct] = *reinterpret_cast<const bf16x8*>(
              bfrag + (size_t)(((ct >> 1) * 4 + (ksh + 2)) * 2 + (ct & 1)) * 512);
    }
    int byte = l15 * 256 + ks * 64 + lk * 16;
    byte ^= ((l15 & 7) << 4);
    const bf16x8 a = *reinterpret_cast<const bf16x8*>(
        reinterpret_cast<const char*>(myl) + byte);
#pragma unroll
    for (int ct = 0; ct < 8; ++ct)
      acc[ct] = __builtin_amdgcn_mfma_f32_16x16x32_bf16(
          breg[ks & 1][ct], a, acc[ct], 0, 0, 0);  // swapped: lane owns row i
  }

  // ---- (5) epilogue: i = rowbase + l15 ; cols ct*16 + lk*4 ----
  const int i = rowbase + l15;
  if (i < N_NODES) {
    float* orow = outp + (size_t)i * C;
#pragma unroll
    for (int ct = 0; ct < 8; ++ct) {
      const int jj4 = ct * 16 + lk * 4;
      const float4 cv4 = *reinterpret_cast<const float4*>(cvS + jj4);
      float4 o;
      o.x = acc[ct][0] + cv4.x;
      o.y = acc[ct][1] + cv4.y;
      o.z = acc[ct][2] + cv4.z;
      o.w = acc[ct][3] + cv4.w;
      *reinterpret_cast<float4*>(orow + jj4) = o;
    }
  }
}

// ---------------------------------------------------------------------------
extern "C" void kernel_launch(void* const* d_in, const int* in_sizes, int n_in,
                              void* d_out, int out_size, void* d_ws, size_t ws_size,
                              hipStream_t stream) {
  const float* feat1 = (const float*)d_in[0];
  const float* feat2 = (const float*)d_in[2];
  const float* wv1 = (const float*)d_in[20];
  const float* bv1 = (const float*)d_in[21];
  const float* wv2 = (const float*)d_in[22];
  const float* bv2 = (const float*)d_in[23];
  const float* wp1 = (const float*)d_in[24];
  const float* bp1 = (const float*)d_in[25];
  const float* wp2 = (const float*)d_in[26];
  const float* bp2 = (const float*)d_in[27];

  float* ws = (float*)d_ws;
  float* out = (float*)d_out;

  prep_kernel<<<dim3(128, 2), 128, 0, stream>>>(
      wv1, bv1, wp1, bp1, wv2, bv2, wp2, bp2, ws);
  main_kernel<<<dim3(NBLK, 2), 256, 0, stream>>>(feat1, feat2, ws, out);
}